// Round 1
// baseline (584.436 us; speedup 1.0000x reference)
//
#include <hip/hip_runtime.h>
#include <stdint.h>

#define NB     4
#define SEQ    2048
#define NH     16
#define DHD    64
#define DM     1024
#define MTOT   (NB*SEQ)     // 8192

typedef __attribute__((ext_vector_type(8))) short bf16x8;
typedef __attribute__((ext_vector_type(4))) float f32x4;

__device__ __forceinline__ short f2bf(float f) {
  uint32_t u = __float_as_uint(f);
  u = (u + 0x7FFFu + ((u >> 16) & 1u)) >> 16;   // RNE, finite inputs only
  return (short)u;
}

__device__ __forceinline__ f32x4 mfma16(bf16x8 a, bf16x8 b, f32x4 c) {
  return __builtin_amdgcn_mfma_f32_16x16x32_bf16(a, b, c, 0, 0, 0);
}

__device__ __forceinline__ void async16(const void* g, void* l) {
  __builtin_amdgcn_global_load_lds(
      (const __attribute__((address_space(1))) void*)g,
      (__attribute__((address_space(3))) void*)l, 16, 0, 0);
}

// ---- cast x f32 -> bf16 ----
__global__ void k_cast(const float* __restrict__ in, short* __restrict__ out, int n) {
  int i = (blockIdx.x * blockDim.x + threadIdx.x) * 8;
  if (i >= n) return;
  float4 a = *reinterpret_cast<const float4*>(in + i);
  float4 b = *reinterpret_cast<const float4*>(in + i + 4);
  bf16x8 v;
  v[0] = f2bf(a.x); v[1] = f2bf(a.y); v[2] = f2bf(a.z); v[3] = f2bf(a.w);
  v[4] = f2bf(b.x); v[5] = f2bf(b.y); v[6] = f2bf(b.z); v[7] = f2bf(b.w);
  *reinterpret_cast<bf16x8*>(out + i) = v;
}

// ---- transpose+cast W [K=1024][N=1024] f32 -> Wt [N][K] bf16 ----
__global__ void k_transpose(const float* __restrict__ in, short* __restrict__ out) {
  __shared__ float tile[32][33];
  int n0 = blockIdx.x * 32, k0 = blockIdx.y * 32;
  int tx = threadIdx.x, ty = threadIdx.y;   // block (32,8)
  #pragma unroll
  for (int i = 0; i < 32; i += 8)
    tile[ty + i][tx] = in[(size_t)(k0 + ty + i) * DM + n0 + tx];
  __syncthreads();
  #pragma unroll
  for (int i = 0; i < 32; i += 8)
    out[(size_t)(n0 + ty + i) * DM + k0 + tx] = f2bf(tile[tx][ty + i]);
}

// ---- 128x128x(K=1024) bf16 MFMA GEMM, B given transposed [N][K] ----
// MODE 0: C bf16 [M][DM]   (Q,K)
// MODE 1: C bf16 written as Vt[b][n][s] = [ (b*DM+n)*SEQ + s ]   (V)
// MODE 2: C f32 [M][DM]    (final output)
template<int MODE>
__global__ void __launch_bounds__(256) k_gemm(const short* __restrict__ A,
                                              const short* __restrict__ Bt,
                                              const float* __restrict__ bias,
                                              void* __restrict__ Cv) {
  __shared__ short lA[128 * 32];
  __shared__ short lB[128 * 32];
  int m0 = blockIdx.x * 128, n0 = blockIdx.y * 128;
  int tid = threadIdx.x, lane = tid & 63, w = tid >> 6;
  int wr = w >> 1, wc = w & 1;
  int l15 = lane & 15, lg = lane >> 4;
  f32x4 acc[4][4] = {};

  int r0 = tid >> 2, c0 = (tid & 3) * 8;                 // chunk 0..255
  int r1 = (tid + 256) >> 2, c1 = ((tid + 256) & 3) * 8; // chunk 256..511
  const short* ga0 = A + (size_t)(m0 + r0) * DM + c0;
  const short* ga1 = A + (size_t)(m0 + r1) * DM + c1;
  const short* gb0 = Bt + (size_t)(n0 + r0) * DM + c0;
  const short* gb1 = Bt + (size_t)(n0 + r1) * DM + c1;
  short* lA0 = lA + w * 512;           // wave-uniform LDS bases (+lane*16B by HW)
  short* lA1 = lA + 2048 + w * 512;
  short* lB0 = lB + w * 512;
  short* lB1 = lB + 2048 + w * 512;

  for (int k0 = 0; k0 < DM; k0 += 32) {
    async16(ga0 + k0, lA0);
    async16(ga1 + k0, lA1);
    async16(gb0 + k0, lB0);
    async16(gb1 + k0, lB1);
    __syncthreads();                    // compiler drains vmcnt before barrier
    bf16x8 af[4], bfr[4];
    #pragma unroll
    for (int i = 0; i < 4; ++i) {
      af[i]  = *reinterpret_cast<const bf16x8*>(lA + (wr * 64 + i * 16 + l15) * 32 + lg * 8);
      bfr[i] = *reinterpret_cast<const bf16x8*>(lB + (wc * 64 + i * 16 + l15) * 32 + lg * 8);
    }
    #pragma unroll
    for (int i = 0; i < 4; ++i)
      #pragma unroll
      for (int j = 0; j < 4; ++j)
        acc[i][j] = mfma16(af[i], bfr[j], acc[i][j]);
    __syncthreads();
  }

  #pragma unroll
  for (int j = 0; j < 4; ++j) {
    int cg = n0 + wc * 64 + j * 16 + l15;
    float bv = bias[cg];
    #pragma unroll
    for (int i = 0; i < 4; ++i) {
      #pragma unroll
      for (int r = 0; r < 4; ++r) {
        int rg = m0 + wr * 64 + i * 16 + lg * 4 + r;
        float val = acc[i][j][r] + bv;
        if (MODE == 0)
          ((short*)Cv)[(size_t)rg * DM + cg] = f2bf(val);
        else if (MODE == 1)
          ((short*)Cv)[((size_t)((rg >> 11) * DM + cg)) * SEQ + (rg & 2047)] = f2bf(val);
        else
          ((float*)Cv)[(size_t)rg * DM + cg] = val;
      }
    }
  }
}

// ---- flash attention with ALiBi + padding mask ----
// grid (SEQ/64, NB*NH), block 256 (4 waves; each wave owns 16 q rows)
__global__ void __launch_bounds__(256) k_attn(const short* __restrict__ Q,
                                              const short* __restrict__ Kb,
                                              const short* __restrict__ Vt,
                                              const int* __restrict__ pmask,
                                              short* __restrict__ O) {
  __shared__ short pl[4][16 * 32];
  int qt = blockIdx.x, bh = blockIdx.y;
  int b = bh >> 4, h = bh & 15;
  int tid = threadIdx.x, lane = tid & 63, w = tid >> 6;
  int l15 = lane & 15, lg = lane >> 4;
  int q0 = qt * 64 + w * 16;
  float slope = exp2f(-0.5f * (float)(h + 1));
  const float c1 = 0.125f;          // 1/sqrt(64)
  float c2 = slope * 0.125f;

  const short* qp = Q + (size_t)(b * SEQ + q0 + l15) * DM + h * DHD + lg * 8;
  bf16x8 aq0 = *reinterpret_cast<const bf16x8*>(qp);
  bf16x8 aq1 = *reinterpret_cast<const bf16x8*>(qp + 32);

  const short* kbase = Kb + (size_t)(b * SEQ) * DM + h * DHD;
  const short* vbase = Vt + (size_t)bh * DHD * SEQ;
  const int* pmb = pmask + b * SEQ;

  float m[4], ssum[4];
  f32x4 acc[4] = {};
  #pragma unroll
  for (int r = 0; r < 4; ++r) { m[r] = -1e30f; ssum[r] = 0.0f; }
  float qi[4];
  #pragma unroll
  for (int r = 0; r < 4; ++r) qi[r] = (float)(q0 + lg * 4 + r);

  for (int kt = 0; kt < SEQ; kt += 32) {
    const short* kp = kbase + (size_t)(kt + l15) * DM + lg * 8;
    bf16x8 k00 = *reinterpret_cast<const bf16x8*>(kp);
    bf16x8 k01 = *reinterpret_cast<const bf16x8*>(kp + 32);
    bf16x8 k10 = *reinterpret_cast<const bf16x8*>(kp + (size_t)16 * DM);
    bf16x8 k11 = *reinterpret_cast<const bf16x8*>(kp + (size_t)16 * DM + 32);
    f32x4 s0 = {}, s1 = {};
    s0 = mfma16(aq0, k00, s0);
    s0 = mfma16(aq1, k01, s0);
    s1 = mfma16(aq0, k10, s1);
    s1 = mfma16(aq1, k11, s1);

    float j0f = (float)(kt + l15), j1f = j0f + 16.0f;
    bool v0 = pmb[kt + l15] != 0;
    bool v1 = pmb[kt + 16 + l15] != 0;
    float l0[4], l1[4], tmax[4];
    #pragma unroll
    for (int r = 0; r < 4; ++r) {
      l0[r] = v0 ? (s0[r] * c1 - c2 * fabsf(qi[r] - j0f)) : -1e30f;
      l1[r] = v1 ? (s1[r] * c1 - c2 * fabsf(qi[r] - j1f)) : -1e30f;
      tmax[r] = fmaxf(l0[r], l1[r]);
    }
    #pragma unroll
    for (int d = 1; d < 16; d <<= 1)
      #pragma unroll
      for (int r = 0; r < 4; ++r)
        tmax[r] = fmaxf(tmax[r], __shfl_xor(tmax[r], d));

    float f[4], p0[4], p1[4], rs[4];
    #pragma unroll
    for (int r = 0; r < 4; ++r) {
      float mn = fmaxf(m[r], tmax[r]);
      f[r] = __expf(m[r] - mn);
      m[r] = mn;
      p0[r] = __expf(l0[r] - mn);
      p1[r] = __expf(l1[r] - mn);
      rs[r] = p0[r] + p1[r];
    }
    #pragma unroll
    for (int d = 1; d < 16; d <<= 1)
      #pragma unroll
      for (int r = 0; r < 4; ++r)
        rs[r] += __shfl_xor(rs[r], d);
    #pragma unroll
    for (int r = 0; r < 4; ++r) {
      ssum[r] = ssum[r] * f[r] + rs[r];
      #pragma unroll
      for (int d = 0; d < 4; ++d) acc[d][r] *= f[r];
    }

    // P (D-layout) -> LDS -> A-fragment layout
    short* pw = pl[w];
    __syncthreads();
    #pragma unroll
    for (int r = 0; r < 4; ++r) {
      pw[(lg * 4 + r) * 32 + l15]      = f2bf(p0[r]);
      pw[(lg * 4 + r) * 32 + l15 + 16] = f2bf(p1[r]);
    }
    __syncthreads();
    bf16x8 pf = *reinterpret_cast<const bf16x8*>(pw + l15 * 32 + lg * 8);

    #pragma unroll
    for (int d = 0; d < 4; ++d) {
      bf16x8 vf = *reinterpret_cast<const bf16x8*>(vbase + (size_t)(d * 16 + l15) * SEQ + kt + lg * 8);
      acc[d] = mfma16(pf, vf, acc[d]);
    }
  }

  #pragma unroll
  for (int r = 0; r < 4; ++r) {
    float inv = 1.0f / ssum[r];
    short* op = O + (size_t)(b * SEQ + q0 + lg * 4 + r) * DM + h * DHD;
    #pragma unroll
    for (int d = 0; d < 4; ++d)
      op[d * 16 + l15] = f2bf(acc[d][r] * inv);
  }
}

extern "C" void kernel_launch(void* const* d_in, const int* in_sizes, int n_in,
                              void* d_out, int out_size, void* d_ws, size_t ws_size,
                              hipStream_t stream) {
  const float* x  = (const float*)d_in[0];
  const float* Wq = (const float*)d_in[1];
  const float* bq = (const float*)d_in[2];
  const float* Wk = (const float*)d_in[3];
  const float* bk = (const float*)d_in[4];
  const float* Wv = (const float*)d_in[5];
  const float* bv = (const float*)d_in[6];
  const float* Wo = (const float*)d_in[7];
  const float* bo = (const float*)d_in[8];
  const int*   pm = (const int*)d_in[9];

  char* ws = (char*)d_ws;
  const size_t MB = 1ull << 20;
  short* xb  = (short*)(ws + 0 * MB);    // 16 MB: x bf16
  short* q   = (short*)(ws + 16 * MB);   // 16 MB
  short* k   = (short*)(ws + 32 * MB);   // 16 MB
  short* vt  = (short*)(ws + 48 * MB);   // 16 MB, [b,h,dh,s]
  short* ob  = (short*)(ws + 64 * MB);   // 16 MB: attention out bf16
  short* wqt = (short*)(ws + 80 * MB);   // 2 MB each
  short* wkt = (short*)(ws + 82 * MB);
  short* wvt = (short*)(ws + 84 * MB);
  short* wot = (short*)(ws + 86 * MB);   // ends at 88 MB

  k_cast<<<dim3(MTOT * DM / 8 / 256), dim3(256), 0, stream>>>(x, xb, MTOT * DM);
  k_transpose<<<dim3(32, 32), dim3(32, 8), 0, stream>>>(Wq, wqt);
  k_transpose<<<dim3(32, 32), dim3(32, 8), 0, stream>>>(Wk, wkt);
  k_transpose<<<dim3(32, 32), dim3(32, 8), 0, stream>>>(Wv, wvt);
  k_transpose<<<dim3(32, 32), dim3(32, 8), 0, stream>>>(Wo, wot);
  k_gemm<0><<<dim3(64, 8), dim3(256), 0, stream>>>(xb, wqt, bq, q);
  k_gemm<0><<<dim3(64, 8), dim3(256), 0, stream>>>(xb, wkt, bk, k);
  k_gemm<1><<<dim3(64, 8), dim3(256), 0, stream>>>(xb, wvt, bv, vt);
  k_attn<<<dim3(SEQ / 64, NB * NH), dim3(256), 0, stream>>>(q, k, vt, pm, ob);
  k_gemm<2><<<dim3(64, 8), dim3(256), 0, stream>>>(ob, wot, bo, d_out);
}